// Round 5
// baseline (5216.192 us; speedup 1.0000x reference)
//
#include <hip/hip_runtime.h>

// SRU stacked RNN, MI355X persistent-pipeline design. Round 7 (= round 6 with
// the LDS budget fixed).
// Round 6 failed to compile: Wt(131072) + red(49152, comment undersold it) +
// hst(3072) = 183296 B > 163840 B. Fix: Wt is DEAD after the one-time B-frag
// register preload, so red+hst now OVERLAY the Wt block (union via char[]),
// with one extra __syncthreads() between the last Wt read and first red write.
// Total LDS = 131072 B.
// Design (unchanged from round 6):
//  1. B-fragments in REGISTERS: each wave preloads its 32 f16x8 B-frags
//     (128 VGPR) once. Steady-state LDS B-traffic (512 KB/block-step through
//     one 128B/clk pipe + 1.35e8 conflict cycles) -> ZERO.
//     Waves: 4 K-quarters x 2 row-halves (32 rows/wave).
//  2. Single-exposure batched A-loads: 16 global_load_dwordx4 (imm offsets)
//     -> one vmcnt(0)+sched_barrier -> 32 MFMAs. 2 exposures/step (was 4).
//  3. Wide sc0sc1 h-stores via LDS transpose; per-(l,rh) flag lines;
//     two-phase backoff gather-poll + slack tracking; write-once ring;
//     double-buffered red + single barrier per step.
// Requires ws_size >= ~161 MB (ring 128 MB + ctrl 4 KB + x16 32 MB).

typedef _Float16 f16;
typedef _Float16 f16x8 __attribute__((ext_vector_type(8)));
typedef _Float16 f16x4 __attribute__((ext_vector_type(4)));
typedef float    floatx4 __attribute__((ext_vector_type(4)));

#define T_ 256
#define B_ 64
#define L_ 4
#define H_ 1024
#define IN_ 1024
#define K_ 2048

#define PANEL (B_*H_)                             // 65536 f16 per (layer,t) slot
#define RING_BYTES ((size_t)L_*T_*PANEL*2)        // 128 MB, slots never recycled
#define CTRL_OFF   RING_BYTES
#define CTRL_BYTES 4096                           // 8 flag lines x 256B
#define X16_OFF    (CTRL_OFF + 65536)             // 64KB-aligned tail

// ---------------- x fp32 -> fp16 ----------------
__global__ void convert_x_kernel(const float* __restrict__ x, f16* __restrict__ x16) {
  const int nvec = (T_*B_*IN_)/4;
  const int stride = gridDim.x*blockDim.x;
  for (int v = blockIdx.x*blockDim.x + threadIdx.x; v < nvec; v += stride) {
    floatx4 in = ((const floatx4*)x)[v];
    f16x4 o; o.x = (f16)in.x; o.y = (f16)in.y; o.z = (f16)in.z; o.w = (f16)in.w;
    ((f16x4*)x16)[v] = o;
  }
}

// Two-phase gather-poll: immediate check, coarse sleep once, then fine polls.
template<int CSLP, int FSLP, bool SLACK>
__device__ __forceinline__ unsigned poll_bk(const unsigned int* line, unsigned tgt) {
  const unsigned int* p = line + (threadIdx.x & 63);
  unsigned v = __hip_atomic_load(p, __ATOMIC_RELAXED, __HIP_MEMORY_SCOPE_SYSTEM);
  if (!__all((int)(v >= tgt))) {
    __builtin_amdgcn_s_sleep(CSLP);
    for (;;) {
      v = __hip_atomic_load(p, __ATOMIC_RELAXED, __HIP_MEMORY_SCOPE_SYSTEM);
      if (__all((int)(v >= tgt))) break;
      __builtin_amdgcn_s_sleep(FSLP);
    }
  }
  unsigned a = tgt;
  if (SLACK) {
    if      (__all((int)(v >= tgt + 16))) a = tgt + 16;
    else if (__all((int)(v >= tgt + 4)))  a = tgt + 4;
    else if (__all((int)(v >= tgt + 1)))  a = tgt + 1;
  }
  asm volatile("" ::: "memory");   // keep dependent A-loads below the poll
  return a;
}

// 16 cached 16B loads from one base pointer, immediate offsets, NO waitcnt.
#define GLB_LOAD16(A, p)                                                     \
  asm volatile(                                                              \
    "global_load_dwordx4 %0, %16, off\n\t"                                   \
    "global_load_dwordx4 %1, %16, off offset:64\n\t"                         \
    "global_load_dwordx4 %2, %16, off offset:128\n\t"                        \
    "global_load_dwordx4 %3, %16, off offset:192\n\t"                        \
    "global_load_dwordx4 %4, %16, off offset:256\n\t"                        \
    "global_load_dwordx4 %5, %16, off offset:320\n\t"                        \
    "global_load_dwordx4 %6, %16, off offset:384\n\t"                        \
    "global_load_dwordx4 %7, %16, off offset:448\n\t"                        \
    "global_load_dwordx4 %8, %16, off offset:512\n\t"                        \
    "global_load_dwordx4 %9, %16, off offset:576\n\t"                        \
    "global_load_dwordx4 %10, %16, off offset:640\n\t"                       \
    "global_load_dwordx4 %11, %16, off offset:704\n\t"                       \
    "global_load_dwordx4 %12, %16, off offset:768\n\t"                       \
    "global_load_dwordx4 %13, %16, off offset:832\n\t"                       \
    "global_load_dwordx4 %14, %16, off offset:896\n\t"                       \
    "global_load_dwordx4 %15, %16, off offset:960"                           \
    : "=&v"(A[0]),"=&v"(A[1]),"=&v"(A[2]),"=&v"(A[3]),                       \
      "=&v"(A[4]),"=&v"(A[5]),"=&v"(A[6]),"=&v"(A[7]),                       \
      "=&v"(A[8]),"=&v"(A[9]),"=&v"(A[10]),"=&v"(A[11]),                     \
      "=&v"(A[12]),"=&v"(A[13]),"=&v"(A[14]),"=&v"(A[15])                    \
    : "v"((const void*)(p)) : "memory")

// rule 18: sched_barrier after an inline-asm waitcnt, or MFMAs get hoisted.
#define WAITV0 do {                                                          \
    asm volatile("s_waitcnt vmcnt(0)" ::: "memory");                         \
    __builtin_amdgcn_sched_barrier(0);                                       \
  } while (0)

// LDS overlay types
typedef f16   wt_t[32][2048];                  // 131072 B (phase 0 only)
typedef float red_t[2][3][2][2][2][64][4];     // 49152 B  (steady state)
typedef f16   hst_t[64][24];                   // 3072 B   (steady state)

// ---------------- main persistent kernel ----------------
__global__ __launch_bounds__(512, 2) void sru_main(
    const float* __restrict__ W,      // [L][2048][2048]
    const float* __restrict__ bias,   // [L][2048]
    const f16*  __restrict__ x16,     // [T][64][1024]
    f16*        __restrict__ ring,    // [L][T][64*1024], write-once slots
    unsigned int* __restrict__ done,  // [L][2rh][64c] flag slots
    float*      __restrict__ out)     // [T*64*1024 outputs][L*64*1024 h_final]
{
  __shared__ __align__(16) char smem[131072];  // Wt overlaid by red+hst
  wt_t&  Wt  = *reinterpret_cast<wt_t*>(smem);
  red_t& red = *reinterpret_cast<red_t*>(smem);
  hst_t& hst = *reinterpret_cast<hst_t*>(smem + sizeof(red_t));  // 49152..52224

  const int bid  = blockIdx.x;
  const int l    = bid >> 6;
  const int c    = bid & 63;
  const int n0   = c*16;
  const int tid  = threadIdx.x;
  const int lane = tid & 63;
  const int quad = lane >> 4;
  const int lc   = lane & 15;
  const int w    = tid >> 6;         // wave 0..7
  const int kq   = w & 3;            // K-quarter: 0,1 = x half; 2,3 = h half
  const int rh   = w >> 2;           // row half (32 batch rows)
  const int R    = rh*32;

  // ---- phase 0: stage W slice into LDS (read back once, then LDS reused) --
  {
    const int jj = tid & 15;
    const int k0 = tid >> 4;                  // 0..31
    const float* Wl = W + (size_t)l*K_*2048;
    for (int i = 0; i < 64; ++i) {
      int k = k0 + i*32;
      Wt[jj][k]      = (f16)Wl[(size_t)k*2048 + n0 + jj];
      Wt[16 + jj][k] = (f16)Wl[(size_t)k*2048 + 1024 + n0 + jj];
    }
  }
  const float bl = bias[l*2048 + n0 + lc];
  const float bf = bias[l*2048 + 1024 + n0 + lc];
  __syncthreads();

  // ---- preload this wave's B-fragments into registers (loop-invariant) ----
  // lane (lc,quad): learn col n0+lc (Wt row lc), forget col (Wt row 16+lc),
  // K = kq*512 + quad*8 + j*32 .. +8, j = 0..15.
  f16x8 bL[16], bF[16];
  {
    const int kw = kq*512 + quad*8;
    #pragma unroll
    for (int j = 0; j < 16; ++j) {
      bL[j] = *(const f16x8*)&Wt[lc][kw + j*32];
      bF[j] = *(const f16x8*)&Wt[16 + lc][kw + j*32];
    }
  }
  __syncthreads();   // Wt dead beyond this point; red/hst may now reuse the LDS

  floatx4 hreg0 = 0.f, hreg1 = 0.f;  // finisher (kq0) persistent h, rt0/rt1

  const bool useH = (kq >= 2);
  const int  aloc = (kq & 1)*512 + quad*8;   // K offset within the 1024-wide panel

  unsigned int* lineL = done + ((l*2 + rh) << 6);
  unsigned int* lineP = (l > 0) ? done + (((l-1)*2 + rh) << 6) : (unsigned int*)0;
  unsigned avail = 0;

  for (int t = 0; t < T_; ++t) {
    // --- per-wave waits ---
    if (!useH) {
      if (l > 0 && avail < (unsigned)(t+1))
        avail = poll_bk<16, 4, true>(lineP, (unsigned)(t+1));
    } else {
      if (t > 0) (void)poll_bk<32, 4, false>(lineL, (unsigned)t);
    }

    floatx4 accL0 = 0.f, accL1 = 0.f, accF0 = 0.f, accF1 = 0.f;

    if (!(useH && t == 0)) {           // t==0 h-part is exactly zero: skip
      const f16* Abase;
      if (useH)        Abase = ring + (size_t)(l*T_ + (t-1))*PANEL;
      else if (l == 0) Abase = x16 + (size_t)t*PANEL;
      else             Abase = ring + (size_t)((l-1)*T_ + t)*PANEL;
      const f16* ap0 = Abase + (size_t)(R + lc)*H_ + aloc;   // rows R..R+15
      const f16* ap1 = ap0 + 16*H_;                          // rows R+16..R+31

      floatx4 ar[16];
      GLB_LOAD16(ar, ap0);             // 16 loads in flight, ONE exposure
      WAITV0;
      #pragma unroll
      for (int j = 0; j < 16; ++j) {
        f16x8 av = __builtin_bit_cast(f16x8, ar[j]);
        accL0 = __builtin_amdgcn_mfma_f32_16x16x32_f16(av, bL[j], accL0, 0,0,0);
        accF0 = __builtin_amdgcn_mfma_f32_16x16x32_f16(av, bF[j], accF0, 0,0,0);
      }
      GLB_LOAD16(ar, ap1);
      WAITV0;
      #pragma unroll
      for (int j = 0; j < 16; ++j) {
        f16x8 av = __builtin_bit_cast(f16x8, ar[j]);
        accL1 = __builtin_amdgcn_mfma_f32_16x16x32_f16(av, bL[j], accL1, 0,0,0);
        accF1 = __builtin_amdgcn_mfma_f32_16x16x32_f16(av, bF[j], accF1, 0,0,0);
      }
    }

    if (kq != 0) {                     // publish partial to red[t&1]
      const int s = kq - 1;
      *(floatx4*)&red[t&1][s][rh][0][0][lane][0] = accL0;
      *(floatx4*)&red[t&1][s][rh][0][1][lane][0] = accF0;
      *(floatx4*)&red[t&1][s][rh][1][0][lane][0] = accL1;
      *(floatx4*)&red[t&1][s][rh][1][1][lane][0] = accF1;
    }
    __syncthreads();                   // the ONLY barrier per step

    if (kq == 0) {
      #pragma unroll
      for (int s = 0; s < 3; ++s) {
        accL0 += *(const floatx4*)&red[t&1][s][rh][0][0][lane][0];
        accF0 += *(const floatx4*)&red[t&1][s][rh][0][1][lane][0];
        accL1 += *(const floatx4*)&red[t&1][s][rh][1][0][lane][0];
        accF1 += *(const floatx4*)&red[t&1][s][rh][1][1][lane][0];
      }
      f16* ringw = ring + (size_t)(l*T_ + t)*PANEL;

      #pragma unroll
      for (int rt = 0; rt < 2; ++rt) {
        #pragma unroll
        for (int r = 0; r < 4; ++r) {
          float zl = (rt ? accL1[r] : accL0[r]) + bl;
          float zf = (rt ? accF1[r] : accF0[r]) + bf;
          float fg = 1.0f/(1.0f + __expf(-zf));
          float th = 1.0f - 2.0f/(__expf(2.0f*zl) + 1.0f);
          float hv = rt ? hreg1[r] : hreg0[r];
          float hn = fg*hv + (1.0f - fg)*th;
          if (rt) hreg1[r] = hn; else hreg0[r] = hn;
          hst[R + rt*16 + quad*4 + r][lc] = (f16)hn;
        }
      }
      // same-wave LDS RAW: transpose reads must wait for the writes
      asm volatile("s_waitcnt lgkmcnt(0)" ::: "memory");
      __builtin_amdgcn_sched_barrier(0);

      {                                 // 32 rows x 2 halves = 64 x 16B stores
        int srow = R + (lane >> 1);
        int sh   = lane & 1;
        floatx4 hv = *(const floatx4*)&hst[srow][sh*8];
        asm volatile("global_store_dwordx4 %0, %1, off sc0 sc1"
                     :: "v"((void*)(ringw + (size_t)srow*H_ + n0 + sh*8)),
                        "v"(hv) : "memory");
      }
      asm volatile("s_waitcnt vmcnt(0)" ::: "memory");   // drain own wide stores
      if (lane == 0)
        __hip_atomic_store(lineL + c, (unsigned)(t+1),
                           __ATOMIC_RELAXED, __HIP_MEMORY_SCOPE_SYSTEM);

      // off-critical-path outputs (plain cached stores)
      if (l == 3) {
        #pragma unroll
        for (int rt = 0; rt < 2; ++rt)
          #pragma unroll
          for (int r = 0; r < 4; ++r)
            out[(size_t)t*PANEL + (size_t)(R + rt*16 + quad*4 + r)*H_ + n0 + lc]
              = rt ? hreg1[r] : hreg0[r];
      }
      if (t == T_ - 1) {
        #pragma unroll
        for (int rt = 0; rt < 2; ++rt)
          #pragma unroll
          for (int r = 0; r < 4; ++r)
            out[(size_t)T_*PANEL + (size_t)l*PANEL
                + (size_t)(R + rt*16 + quad*4 + r)*H_ + n0 + lc]
              = rt ? hreg1[r] : hreg0[r];
      }
    }
    // No second barrier: red is double-buffered (writers touch red[t&1] again
    // only after barrier(t+1), by which time this step's readers are done).
  }
}

extern "C" void kernel_launch(void* const* d_in, const int* in_sizes, int n_in,
                              void* d_out, int out_size, void* d_ws, size_t ws_size,
                              hipStream_t stream) {
  (void)in_sizes; (void)n_in; (void)out_size; (void)ws_size;
  const float* x = (const float*)d_in[0];
  const float* W = (const float*)d_in[2];
  const float* b = (const float*)d_in[3];
  float* out = (float*)d_out;

  char* ws = (char*)d_ws;
  f16* ring = (f16*)ws;
  unsigned int* done = (unsigned int*)(ws + CTRL_OFF);
  f16* x16 = (f16*)(ws + X16_OFF);

  hipMemsetAsync(ws + CTRL_OFF, 0, CTRL_BYTES, stream);
  convert_x_kernel<<<1024, 256, 0, stream>>>(x, x16);

  void* args[] = { (void*)&W, (void*)&b, (void*)&x16, (void*)&ring, (void*)&done, (void*)&out };
  hipLaunchCooperativeKernel((const void*)sru_main, dim3(256), dim3(512), args, 0, stream);
}

// Round 7
// 5206.235 us; speedup vs baseline: 1.0019x; 1.0019x over previous
//
#include <hip/hip_runtime.h>

// SRU stacked RNN, MI355X persistent-pipeline design. Round 9 (= round 8
// resubmitted verbatim; round 8's bench was an infra failure "container
// failed twice" -- no compile/test evidence against the kernel).
// Round 7 (5216 us) was a REGISTER SPILL, not a design failure:
//   VGPR_Count=128 == the 4-waves/EU allocation boundary; demand ~230/wave
//   (bL[16]+bF[16]=128 persistent B-frags + ar[16]=64 + acc/addr). The
//   compiler honored __launch_bounds__(512,2) as a 2-blocks/CU target, capped
//   at 128 VGPR, and spilled the B-frags to scratch -> every step re-loads
//   them from HBM: FETCH 746 MB -> 7.3 GB, 1516 GB/s of scratch traffic on
//   the MFMA critical path.
// Fix (single change): __launch_bounds__(512, 1) -> 1 block/CU (what the
// 256-block cooperative launch needs anyway; LDS 131 KB pins it regardless)
// -> 256-VGPR cap -> no spill.
// Design (unchanged from round 7):
//  1. B-fragments in REGISTERS: each wave preloads its 32 f16x8 B-frags once;
//     steady-state LDS B-traffic (and its 1.35e8 conflict cycles) -> ~0
//     (confirmed: conflicts 1.35e8 -> 1.02e7 in round 7).
//     Waves: 4 K-quarters x 2 row-halves (32 rows/wave).
//  2. Single-exposure batched A-loads: 16 global_load_dwordx4 (imm offsets)
//     -> one vmcnt(0)+sched_barrier -> 32 MFMAs. 2 exposures/step.
//  3. Wide sc0sc1 h-stores via LDS transpose; per-(l,rh) flag lines;
//     two-phase backoff gather-poll + slack tracking; write-once ring;
//     double-buffered red + single barrier per step; red/hst overlay dead Wt.
// Requires ws_size >= ~161 MB (ring 128 MB + ctrl 4 KB + x16 32 MB).

typedef _Float16 f16;
typedef _Float16 f16x8 __attribute__((ext_vector_type(8)));
typedef _Float16 f16x4 __attribute__((ext_vector_type(4)));
typedef float    floatx4 __attribute__((ext_vector_type(4)));

#define T_ 256
#define B_ 64
#define L_ 4
#define H_ 1024
#define IN_ 1024
#define K_ 2048

#define PANEL (B_*H_)                             // 65536 f16 per (layer,t) slot
#define RING_BYTES ((size_t)L_*T_*PANEL*2)        // 128 MB, slots never recycled
#define CTRL_OFF   RING_BYTES
#define CTRL_BYTES 4096                           // 8 flag lines x 256B
#define X16_OFF    (CTRL_OFF + 65536)             // 64KB-aligned tail

// ---------------- x fp32 -> fp16 ----------------
__global__ void convert_x_kernel(const float* __restrict__ x, f16* __restrict__ x16) {
  const int nvec = (T_*B_*IN_)/4;
  const int stride = gridDim.x*blockDim.x;
  for (int v = blockIdx.x*blockDim.x + threadIdx.x; v < nvec; v += stride) {
    floatx4 in = ((const floatx4*)x)[v];
    f16x4 o; o.x = (f16)in.x; o.y = (f16)in.y; o.z = (f16)in.z; o.w = (f16)in.w;
    ((f16x4*)x16)[v] = o;
  }
}

// Two-phase gather-poll: immediate check, coarse sleep once, then fine polls.
template<int CSLP, int FSLP, bool SLACK>
__device__ __forceinline__ unsigned poll_bk(const unsigned int* line, unsigned tgt) {
  const unsigned int* p = line + (threadIdx.x & 63);
  unsigned v = __hip_atomic_load(p, __ATOMIC_RELAXED, __HIP_MEMORY_SCOPE_SYSTEM);
  if (!__all((int)(v >= tgt))) {
    __builtin_amdgcn_s_sleep(CSLP);
    for (;;) {
      v = __hip_atomic_load(p, __ATOMIC_RELAXED, __HIP_MEMORY_SCOPE_SYSTEM);
      if (__all((int)(v >= tgt))) break;
      __builtin_amdgcn_s_sleep(FSLP);
    }
  }
  unsigned a = tgt;
  if (SLACK) {
    if      (__all((int)(v >= tgt + 16))) a = tgt + 16;
    else if (__all((int)(v >= tgt + 4)))  a = tgt + 4;
    else if (__all((int)(v >= tgt + 1)))  a = tgt + 1;
  }
  asm volatile("" ::: "memory");   // keep dependent A-loads below the poll
  return a;
}

// 16 cached 16B loads from one base pointer, immediate offsets, NO waitcnt.
#define GLB_LOAD16(A, p)                                                     \
  asm volatile(                                                              \
    "global_load_dwordx4 %0, %16, off\n\t"                                   \
    "global_load_dwordx4 %1, %16, off offset:64\n\t"                         \
    "global_load_dwordx4 %2, %16, off offset:128\n\t"                        \
    "global_load_dwordx4 %3, %16, off offset:192\n\t"                        \
    "global_load_dwordx4 %4, %16, off offset:256\n\t"                        \
    "global_load_dwordx4 %5, %16, off offset:320\n\t"                        \
    "global_load_dwordx4 %6, %16, off offset:384\n\t"                        \
    "global_load_dwordx4 %7, %16, off offset:448\n\t"                        \
    "global_load_dwordx4 %8, %16, off offset:512\n\t"                        \
    "global_load_dwordx4 %9, %16, off offset:576\n\t"                        \
    "global_load_dwordx4 %10, %16, off offset:640\n\t"                       \
    "global_load_dwordx4 %11, %16, off offset:704\n\t"                       \
    "global_load_dwordx4 %12, %16, off offset:768\n\t"                       \
    "global_load_dwordx4 %13, %16, off offset:832\n\t"                       \
    "global_load_dwordx4 %14, %16, off offset:896\n\t"                       \
    "global_load_dwordx4 %15, %16, off offset:960"                           \
    : "=&v"(A[0]),"=&v"(A[1]),"=&v"(A[2]),"=&v"(A[3]),                       \
      "=&v"(A[4]),"=&v"(A[5]),"=&v"(A[6]),"=&v"(A[7]),                       \
      "=&v"(A[8]),"=&v"(A[9]),"=&v"(A[10]),"=&v"(A[11]),                     \
      "=&v"(A[12]),"=&v"(A[13]),"=&v"(A[14]),"=&v"(A[15])                    \
    : "v"((const void*)(p)) : "memory")

// rule 18: sched_barrier after an inline-asm waitcnt, or MFMAs get hoisted.
#define WAITV0 do {                                                          \
    asm volatile("s_waitcnt vmcnt(0)" ::: "memory");                         \
    __builtin_amdgcn_sched_barrier(0);                                       \
  } while (0)

// LDS overlay types
typedef f16   wt_t[32][2048];                  // 131072 B (phase 0 only)
typedef float red_t[2][3][2][2][2][64][4];     // 49152 B  (steady state)
typedef f16   hst_t[64][24];                   // 3072 B   (steady state)

// ---------------- main persistent kernel ----------------
__global__ __launch_bounds__(512, 1) void sru_main(
    const float* __restrict__ W,      // [L][2048][2048]
    const float* __restrict__ bias,   // [L][2048]
    const f16*  __restrict__ x16,     // [T][64][1024]
    f16*        __restrict__ ring,    // [L][T][64*1024], write-once slots
    unsigned int* __restrict__ done,  // [L][2rh][64c] flag slots
    float*      __restrict__ out)     // [T*64*1024 outputs][L*64*1024 h_final]
{
  __shared__ __align__(16) char smem[131072];  // Wt overlaid by red+hst
  wt_t&  Wt  = *reinterpret_cast<wt_t*>(smem);
  red_t& red = *reinterpret_cast<red_t*>(smem);
  hst_t& hst = *reinterpret_cast<hst_t*>(smem + sizeof(red_t));  // 49152..52224

  const int bid  = blockIdx.x;
  const int l    = bid >> 6;
  const int c    = bid & 63;
  const int n0   = c*16;
  const int tid  = threadIdx.x;
  const int lane = tid & 63;
  const int quad = lane >> 4;
  const int lc   = lane & 15;
  const int w    = tid >> 6;         // wave 0..7
  const int kq   = w & 3;            // K-quarter: 0,1 = x half; 2,3 = h half
  const int rh   = w >> 2;           // row half (32 batch rows)
  const int R    = rh*32;

  // ---- phase 0: stage W slice into LDS (read back once, then LDS reused) --
  {
    const int jj = tid & 15;
    const int k0 = tid >> 4;                  // 0..31
    const float* Wl = W + (size_t)l*K_*2048;
    for (int i = 0; i < 64; ++i) {
      int k = k0 + i*32;
      Wt[jj][k]      = (f16)Wl[(size_t)k*2048 + n0 + jj];
      Wt[16 + jj][k] = (f16)Wl[(size_t)k*2048 + 1024 + n0 + jj];
    }
  }
  const float bl = bias[l*2048 + n0 + lc];
  const float bf = bias[l*2048 + 1024 + n0 + lc];
  __syncthreads();

  // ---- preload this wave's B-fragments into registers (loop-invariant) ----
  // lane (lc,quad): learn col n0+lc (Wt row lc), forget col (Wt row 16+lc),
  // K = kq*512 + quad*8 + j*32 .. +8, j = 0..15.
  f16x8 bL[16], bF[16];
  {
    const int kw = kq*512 + quad*8;
    #pragma unroll
    for (int j = 0; j < 16; ++j) {
      bL[j] = *(const f16x8*)&Wt[lc][kw + j*32];
      bF[j] = *(const f16x8*)&Wt[16 + lc][kw + j*32];
    }
  }
  __syncthreads();   // Wt dead beyond this point; red/hst may now reuse the LDS

  floatx4 hreg0 = 0.f, hreg1 = 0.f;  // finisher (kq0) persistent h, rt0/rt1

  const bool useH = (kq >= 2);
  const int  aloc = (kq & 1)*512 + quad*8;   // K offset within the 1024-wide panel

  unsigned int* lineL = done + ((l*2 + rh) << 6);
  unsigned int* lineP = (l > 0) ? done + (((l-1)*2 + rh) << 6) : (unsigned int*)0;
  unsigned avail = 0;

  for (int t = 0; t < T_; ++t) {
    // --- per-wave waits ---
    if (!useH) {
      if (l > 0 && avail < (unsigned)(t+1))
        avail = poll_bk<16, 4, true>(lineP, (unsigned)(t+1));
    } else {
      if (t > 0) (void)poll_bk<32, 4, false>(lineL, (unsigned)t);
    }

    floatx4 accL0 = 0.f, accL1 = 0.f, accF0 = 0.f, accF1 = 0.f;

    if (!(useH && t == 0)) {           // t==0 h-part is exactly zero: skip
      const f16* Abase;
      if (useH)        Abase = ring + (size_t)(l*T_ + (t-1))*PANEL;
      else if (l == 0) Abase = x16 + (size_t)t*PANEL;
      else             Abase = ring + (size_t)((l-1)*T_ + t)*PANEL;
      const f16* ap0 = Abase + (size_t)(R + lc)*H_ + aloc;   // rows R..R+15
      const f16* ap1 = ap0 + 16*H_;                          // rows R+16..R+31

      floatx4 ar[16];
      GLB_LOAD16(ar, ap0);             // 16 loads in flight, ONE exposure
      WAITV0;
      #pragma unroll
      for (int j = 0; j < 16; ++j) {
        f16x8 av = __builtin_bit_cast(f16x8, ar[j]);
        accL0 = __builtin_amdgcn_mfma_f32_16x16x32_f16(av, bL[j], accL0, 0,0,0);
        accF0 = __builtin_amdgcn_mfma_f32_16x16x32_f16(av, bF[j], accF0, 0,0,0);
      }
      GLB_LOAD16(ar, ap1);
      WAITV0;
      #pragma unroll
      for (int j = 0; j < 16; ++j) {
        f16x8 av = __builtin_bit_cast(f16x8, ar[j]);
        accL1 = __builtin_amdgcn_mfma_f32_16x16x32_f16(av, bL[j], accL1, 0,0,0);
        accF1 = __builtin_amdgcn_mfma_f32_16x16x32_f16(av, bF[j], accF1, 0,0,0);
      }
    }

    if (kq != 0) {                     // publish partial to red[t&1]
      const int s = kq - 1;
      *(floatx4*)&red[t&1][s][rh][0][0][lane][0] = accL0;
      *(floatx4*)&red[t&1][s][rh][0][1][lane][0] = accF0;
      *(floatx4*)&red[t&1][s][rh][1][0][lane][0] = accL1;
      *(floatx4*)&red[t&1][s][rh][1][1][lane][0] = accF1;
    }
    __syncthreads();                   // the ONLY barrier per step

    if (kq == 0) {
      #pragma unroll
      for (int s = 0; s < 3; ++s) {
        accL0 += *(const floatx4*)&red[t&1][s][rh][0][0][lane][0];
        accF0 += *(const floatx4*)&red[t&1][s][rh][0][1][lane][0];
        accL1 += *(const floatx4*)&red[t&1][s][rh][1][0][lane][0];
        accF1 += *(const floatx4*)&red[t&1][s][rh][1][1][lane][0];
      }
      f16* ringw = ring + (size_t)(l*T_ + t)*PANEL;

      #pragma unroll
      for (int rt = 0; rt < 2; ++rt) {
        #pragma unroll
        for (int r = 0; r < 4; ++r) {
          float zl = (rt ? accL1[r] : accL0[r]) + bl;
          float zf = (rt ? accF1[r] : accF0[r]) + bf;
          float fg = 1.0f/(1.0f + __expf(-zf));
          float th = 1.0f - 2.0f/(__expf(2.0f*zl) + 1.0f);
          float hv = rt ? hreg1[r] : hreg0[r];
          float hn = fg*hv + (1.0f - fg)*th;
          if (rt) hreg1[r] = hn; else hreg0[r] = hn;
          hst[R + rt*16 + quad*4 + r][lc] = (f16)hn;
        }
      }
      // same-wave LDS RAW: transpose reads must wait for the writes
      asm volatile("s_waitcnt lgkmcnt(0)" ::: "memory");
      __builtin_amdgcn_sched_barrier(0);

      {                                 // 32 rows x 2 halves = 64 x 16B stores
        int srow = R + (lane >> 1);
        int sh   = lane & 1;
        floatx4 hv = *(const floatx4*)&hst[srow][sh*8];
        asm volatile("global_store_dwordx4 %0, %1, off sc0 sc1"
                     :: "v"((void*)(ringw + (size_t)srow*H_ + n0 + sh*8)),
                        "v"(hv) : "memory");
      }
      asm volatile("s_waitcnt vmcnt(0)" ::: "memory");   // drain own wide stores
      if (lane == 0)
        __hip_atomic_store(lineL + c, (unsigned)(t+1),
                           __ATOMIC_RELAXED, __HIP_MEMORY_SCOPE_SYSTEM);

      // off-critical-path outputs (plain cached stores)
      if (l == 3) {
        #pragma unroll
        for (int rt = 0; rt < 2; ++rt)
          #pragma unroll
          for (int r = 0; r < 4; ++r)
            out[(size_t)t*PANEL + (size_t)(R + rt*16 + quad*4 + r)*H_ + n0 + lc]
              = rt ? hreg1[r] : hreg0[r];
      }
      if (t == T_ - 1) {
        #pragma unroll
        for (int rt = 0; rt < 2; ++rt)
          #pragma unroll
          for (int r = 0; r < 4; ++r)
            out[(size_t)T_*PANEL + (size_t)l*PANEL
                + (size_t)(R + rt*16 + quad*4 + r)*H_ + n0 + lc]
              = rt ? hreg1[r] : hreg0[r];
      }
    }
    // No second barrier: red is double-buffered (writers touch red[t&1] again
    // only after barrier(t+1), by which time this step's readers are done).
  }
}

extern "C" void kernel_launch(void* const* d_in, const int* in_sizes, int n_in,
                              void* d_out, int out_size, void* d_ws, size_t ws_size,
                              hipStream_t stream) {
  (void)in_sizes; (void)n_in; (void)out_size; (void)ws_size;
  const float* x = (const float*)d_in[0];
  const float* W = (const float*)d_in[2];
  const float* b = (const float*)d_in[3];
  float* out = (float*)d_out;

  char* ws = (char*)d_ws;
  f16* ring = (f16*)ws;
  unsigned int* done = (unsigned int*)(ws + CTRL_OFF);
  f16* x16 = (f16*)(ws + X16_OFF);

  hipMemsetAsync(ws + CTRL_OFF, 0, CTRL_BYTES, stream);
  convert_x_kernel<<<1024, 256, 0, stream>>>(x, x16);

  void* args[] = { (void*)&W, (void*)&b, (void*)&x16, (void*)&ring, (void*)&done, (void*)&out };
  hipLaunchCooperativeKernel((const void*)sru_main, dim3(256), dim3(512), args, 0, stream);
}